// Round 15
// baseline (112.230 us; speedup 1.0000x reference)
//
#include <hip/hip_runtime.h>

#define TT 4
#define BB 32
#define DD 512
#define NN 576
#define EE 16
#define DC 8
#define DCH 64              // D-values per chunk
#define CC 144
#define ROW (EE*CC)         // 2304
#define SZ 42467328UL       // B*N*E*C

typedef float f4 __attribute__((ext_vector_type(4)));

// ---------------- Kernel 1: partial logits (float4 loads, LDS cross-thread reduce) ----------
// grid (32, 8), block 576. Thread (q=tid%144, g=tid/144): token-quad 4q..4q+3,
// d-offsets {g+4k, k=0..15}, pooled over t. 16-B lane loads quadruple bytes in
// flight per vmcnt slot (8 KB/wave at unroll 2 vs R10's 2 KB). Partial sums for
// each token-quad live in 4 threads -> LDS reduce (g=1..3 write, g=0 sums+stores).
__global__ __launch_bounds__(576) void k_part(const float* __restrict__ x,
                                              const float* __restrict__ w,
                                              float* __restrict__ part) {
  const int b   = blockIdx.x;
  const int dc  = blockIdx.y;
  const int tid = threadIdx.x;
  const int q   = tid % 144;           // token-quad
  const int g   = tid / 144;           // d-offset group
  const int d0  = dc * DCH;

  __shared__ f4 wlds[DCH][4];          // this block's w chunk: 64 x 16 = 4 KB
  __shared__ f4 redu[3][4][4][144];    // 110,592 B, lane-contiguous in q

  {
    const f4* wsrc = (const f4*)(w + (size_t)d0 * EE);
    for (int i = tid; i < DCH * 4; i += 576)
      ((f4*)wlds)[i] = wsrc[i];
  }
  __syncthreads();

  const f4* xq = (const f4*)(x + ((size_t)b * DD + d0) * NN);
  const size_t TS4 = (size_t)BB * DD * NN / 4;   // t-plane stride in f4

  f4 acc[4][4];
#pragma unroll
  for (int j = 0; j < 4; ++j)
#pragma unroll
    for (int r = 0; r < 4; ++r) acc[j][r] = (f4)0.f;

#pragma unroll 2
  for (int k = 0; k < 16; ++k) {
    const int dlt = g + 4 * k;
    const size_t off = (size_t)dlt * 144 + q;
    const f4 a0 = xq[off];
    const f4 a1 = xq[off + TS4];
    const f4 a2 = xq[off + 2 * TS4];
    const f4 a3 = xq[off + 3 * TS4];
    const f4 xs = (a0 + a1) + (a2 + a3);
    const f4 wq0 = wlds[dlt][0];
    const f4 wq1 = wlds[dlt][1];
    const f4 wq2 = wlds[dlt][2];
    const f4 wq3 = wlds[dlt][3];
#pragma unroll
    for (int j = 0; j < 4; ++j) {
      const f4 xsj = xs[j];
      acc[j][0] += wq0 * xsj;
      acc[j][1] += wq1 * xsj;
      acc[j][2] += wq2 * xsj;
      acc[j][3] += wq3 * xsj;
    }
  }

  if (g > 0) {
#pragma unroll
    for (int j = 0; j < 4; ++j)
#pragma unroll
      for (int r = 0; r < 4; ++r)
        redu[g - 1][j][r][q] = acc[j][r];
  }
  __syncthreads();
  if (g == 0) {
#pragma unroll
    for (int gg = 0; gg < 3; ++gg)
#pragma unroll
      for (int j = 0; j < 4; ++j)
#pragma unroll
        for (int r = 0; r < 4; ++r)
          acc[j][r] += redu[gg][j][r][q];
#pragma unroll
    for (int j = 0; j < 4; ++j) {
      f4* dst4 = (f4*)(part + (((size_t)b * NN + 4 * q + j) * DC + dc) * EE);
#pragma unroll
      for (int r = 0; r < 4; ++r) dst4[r] = acc[j][r];
    }
  }
}

// ---------------- Kernel 2: softmax, top-2, capacity scan (ballot-based) ----------------
// grid 32 (one per b), block 576 (one per token).
__global__ __launch_bounds__(576) void k_gate(const float* __restrict__ part,
                                              float4* __restrict__ info,
                                              float* __restrict__ lossp) {
  const int b = blockIdx.x;
  const int n = threadIdx.x;
  const int wave = n >> 6, lane = n & 63;

  __shared__ float sprox[9][EE];
  __shared__ int   swc1[9][EE];
  __shared__ int   swc2[9][EE];
  __shared__ int   woff1[9][EE];
  __shared__ int   woff2[9][EE];
  __shared__ float sproxTot[EE];
  __shared__ int   scnt0[EE];
  __shared__ int   sbase2[EE];

  // reduce partials -> logits (mean over T folded as *0.25)
  float l[EE];
#pragma unroll
  for (int e = 0; e < EE; ++e) l[e] = 0.f;
  {
    const float4* p4 = (const float4*)(part + (size_t)(b * NN + n) * (DC * EE));
#pragma unroll
    for (int dc = 0; dc < DC; ++dc) {
#pragma unroll
      for (int q = 0; q < 4; ++q) {
        float4 v = p4[dc * 4 + q];
        l[4*q+0] += v.x; l[4*q+1] += v.y; l[4*q+2] += v.z; l[4*q+3] += v.w;
      }
    }
#pragma unroll
    for (int e = 0; e < EE; ++e) l[e] *= 0.25f;
  }

  // softmax
  float m = l[0];
#pragma unroll
  for (int e = 1; e < EE; ++e) m = fmaxf(m, l[e]);
  float raw[EE]; float s = 0.f;
#pragma unroll
  for (int e = 0; e < EE; ++e) { raw[e] = expf(l[e] - m); s += raw[e]; }
  float inv = 1.f / s;
#pragma unroll
  for (int e = 0; e < EE; ++e) raw[e] *= inv;

  // top-1 / top-2 (first-index tie-break, matching jnp.argmax)
  int e1 = 0; float g1 = raw[0];
#pragma unroll
  for (int e = 1; e < EE; ++e) if (raw[e] > g1) { g1 = raw[e]; e1 = e; }
  int e2 = (e1 == 0) ? 1 : 0; float g2 = raw[e2];
#pragma unroll
  for (int e = 0; e < EE; ++e) if (e != e1 && raw[e] > g2) { g2 = raw[e]; e2 = e; }
  const float denom = g1 + g2 + 1e-9f;
  const float w0 = g1 / denom, w1 = g2 / denom;

  // ballot-based per-expert ranks: for each expert, 64-bit membership mask
  const unsigned long long ltm = (1ull << lane) - 1ull;
  int pre1 = 0, pre2 = 0;
#pragma unroll
  for (int e = 0; e < EE; ++e) {
    unsigned long long m1 = __ballot(e1 == e);
    unsigned long long m2 = __ballot(e2 == e);
    if (lane == 0) { swc1[wave][e] = __popcll(m1); swc2[wave][e] = __popcll(m2); }
    if (e == e1) pre1 = __popcll(m1 & ltm);
    if (e == e2) pre2 = __popcll(m2 & ltm);
  }

  // per-wave proxy (softmax sums) reduce
#pragma unroll
  for (int e = 0; e < EE; ++e) {
    float v = raw[e];
#pragma unroll
    for (int off = 32; off; off >>= 1) v += __shfl_xor(v, off);
    if (lane == 0) sprox[wave][e] = v;
  }
  __syncthreads();

  // cross-wave exclusive scan per expert (16 threads, 9 iters each)
  if (n < EE) {
    int r1 = 0, r2 = 0; float pv = 0.f;
#pragma unroll
    for (int wv = 0; wv < 9; ++wv) {
      woff1[wv][n] = r1; r1 += swc1[wv][n];
      woff2[wv][n] = r2; r2 += swc2[wv][n];
      pv += sprox[wv][n];
    }
    scnt0[n]    = r1;                     // pre-capacity top-1 count (for loss)
    sbase2[n]   = r1 < CC ? r1 : CC;      // post-truncation kept count (k=1 base)
    sproxTot[n] = pv;
  }
  __syncthreads();

  if (n == 0) {
    float S = 0.f;
    for (int e = 0; e < EE; ++e) S += sproxTot[e] * (float)scnt0[e];
    lossp[b] = S / ((float)NN * (float)NN);
  }

  const int p0 = woff1[wave][e1] + pre1;
  const int p1 = sbase2[e2] + woff2[wave][e2] + pre2;

  const int  pos0 = (p0 < CC) ? (e1 * CC + p0) : -1;
  const int  pos1 = (p1 < CC) ? (e2 * CC + p1) : -1;
  const float w0k = (p0 < CC) ? w0 : 0.f;
  const float w1k = (p1 < CC) ? w1 : 0.f;

  float4 o;
  o.x = __int_as_float(pos0);
  o.y = w0k;
  o.z = __int_as_float(pos1);
  o.w = w1k;
  info[b * NN + n] = o;
}

// ---------------- Kernel 3: write dispatch + combine + loss (NT, phase-split) ----------------
__global__ __launch_bounds__(576) void k_write(const float4* __restrict__ info,
                                               const float* __restrict__ lossp,
                                               float* __restrict__ out) {
  const int blk  = blockIdx.x;
  const int tid  = threadIdx.x;
  const int tok0 = blk * 8;

  if (blk == 0 && tid == 0) {
    float sv = 0.f;
    for (int b = 0; b < BB; ++b) sv += lossp[b];
    out[2 * SZ] = 0.5f * sv;   // * E^2 / (B*E) = *0.5
  }

  __shared__ float4 sinfo[8];
  if (tid < 8) sinfo[tid] = info[tok0 + tid];
  __syncthreads();

  const int f0 = tid * 4;

  // phase 1: dispatch rows
#pragma unroll
  for (int it = 0; it < 8; ++it) {
    const float4 inf = sinfo[it];
    const int pos0 = __float_as_int(inf.x);
    const int pos1 = __float_as_int(inf.z);
    f4* disp = (f4*)(out + (size_t)(tok0 + it) * ROW);
    f4 dv = { (f0+0 == pos0 || f0+0 == pos1) ? 1.f : 0.f,
              (f0+1 == pos0 || f0+1 == pos1) ? 1.f : 0.f,
              (f0+2 == pos0 || f0+2 == pos1) ? 1.f : 0.f,
              (f0+3 == pos0 || f0+3 == pos1) ? 1.f : 0.f };
    __builtin_nontemporal_store(dv, &disp[tid]);
  }

  // phase 2: combine rows
#pragma unroll
  for (int it = 0; it < 8; ++it) {
    const float4 inf = sinfo[it];
    const int   pos0 = __float_as_int(inf.x);
    const float w0   = inf.y;
    const int   pos1 = __float_as_int(inf.z);
    const float w1   = inf.w;
    f4* comb = (f4*)(out + SZ + (size_t)(tok0 + it) * ROW);
    f4 cv = { (f0+0 == pos0) ? w0 : ((f0+0 == pos1) ? w1 : 0.f),
              (f0+1 == pos0) ? w0 : ((f0+1 == pos1) ? w1 : 0.f),
              (f0+2 == pos0) ? w0 : ((f0+2 == pos1) ? w1 : 0.f),
              (f0+3 == pos0) ? w0 : ((f0+3 == pos1) ? w1 : 0.f) };
    __builtin_nontemporal_store(cv, &comb[tid]);
  }
}

extern "C" void kernel_launch(void* const* d_in, const int* in_sizes, int n_in,
                              void* d_out, int out_size, void* d_ws, size_t ws_size,
                              hipStream_t stream) {
  const float* x = (const float*)d_in[0];
  const float* w = (const float*)d_in[1];
  float* out = (float*)d_out;

  // ws layout: part (2,359,296 f = 9,437,184 B) | info (18432 float4 = 294,912 B) | lossp (32 f)
  float*  part  = (float*)d_ws;
  float4* info  = (float4*)((char*)d_ws + 9437184);
  float*  lossp = (float*)((char*)d_ws + 9437184 + 294912);

  hipLaunchKernelGGL(k_part,  dim3(BB, DC), dim3(576), 0, stream, x, w, part);
  hipLaunchKernelGGL(k_gate,  dim3(BB),     dim3(576), 0, stream, part, info, lossp);
  hipLaunchKernelGGL(k_write, dim3(BB*NN/8), dim3(576), 0, stream, info, lossp, out);
}